// Round 1
// 259.464 us; speedup vs baseline: 1.1913x; 1.1913x over previous
//
#include <hip/hip_runtime.h>
#include <math.h>

// DiffDispatchLP: batched (256x) PDHG, 400 iters, one WG (8 waves) per item.
// All LDS arrays padded with zero guards so every access is base + constant
// immediate offset (no per-iteration address math, no boundary masks).
//
// R1 change: the 6-step __shfl_xor (ds_swizzle, ~40-120cy dependent latency
// each) reductions -- wave 7's total-charge row every PDHG iteration, and the
// power-iteration norm on all waves -- are replaced with a DPP-based VALU
// reduction (row_shr 1/2/4/8 + row_bcast 15/31 + readlane 63, ~10cy/step).
// Theory: wave 7's cross-lane DS chain was the phase-B straggler all other
// waves waited on at the barrier.
//
// sy layout (dwords), each region = [4 guard][data][guard...] stride 104:
//   VB[v] at 624v: MD1@0 MD2@104 MD3@208 MS@312 BY@416 SW@520   (v=0,1)
//   EQ@1248  BS@1352  BCD@1456 (c@1456,d@1560)  UC@1664 (uc,ud)  TC@1872
// sxb layout: C@0 D@104 YC@208 YD@312 S@416  (slot = region + 4 + t)

#define NITER 400
#define PITER 10
#define NY 1874
#define NX 520

// Full wave64 sum via DPP (VALU pipe, no LDS/ds_swizzle traffic).
// Steps: row_shr:1/2/4/8 fold within each 16-lane row (bound_ctrl=1 zero-fills),
// row_bcast15 (rows 1,3 += prev row's lane15 = prev row sum),
// row_bcast31 (rows 2,3 += lane31 = rows0+1 total) -> lane 63 holds the total.
__device__ __forceinline__ float wave_sum64(float v) {
  float r = v;
  int x;
  x = __builtin_amdgcn_update_dpp(0, __float_as_int(r), 0x111, 0xf, 0xf, true); // row_shr:1
  r += __int_as_float(x);
  x = __builtin_amdgcn_update_dpp(0, __float_as_int(r), 0x112, 0xf, 0xf, true); // row_shr:2
  r += __int_as_float(x);
  x = __builtin_amdgcn_update_dpp(0, __float_as_int(r), 0x114, 0xf, 0xf, true); // row_shr:4
  r += __int_as_float(x);
  x = __builtin_amdgcn_update_dpp(0, __float_as_int(r), 0x118, 0xf, 0xf, true); // row_shr:8
  r += __int_as_float(x);
  x = __builtin_amdgcn_update_dpp(0, __float_as_int(r), 0x142, 0xa, 0xf, true); // row_bcast:15 -> rows 1,3
  r += __int_as_float(x);
  x = __builtin_amdgcn_update_dpp(0, __float_as_int(r), 0x143, 0xc, 0xf, true); // row_bcast:31 -> rows 2,3
  r += __int_as_float(x);
  return __int_as_float(__builtin_amdgcn_readlane(__float_as_int(r), 63));
}

__global__ __launch_bounds__(512, 1)
void lp_solve_kernel(const float* __restrict__ price, float* __restrict__ out) {
  __shared__ float sy[NY];
  __shared__ float sxb[NX];
  __shared__ float s_red[8];

  const int tid = threadIdx.x, lane = tid & 63, wid = tid >> 6, bi = blockIdx.x;
  const double ETA_D = sqrt(0.91);
  const float cET = (float)(-(ETA_D * 0.25));  // -ETA*DT
  const float cDE = (float)(0.25 / ETA_D);     // DT/ETA

  // ================= phase A per-thread constants =================
  const bool colAct = (tid < 480);
  const int col = colAct ? tid : 479;
  const int vty = col / 96;            // 0 c, 1 d, 2 yc, 3 yd, 4 soc
  const int t = col - 96 * vty;
  const int wX = 104 * vty + 4 + t;    // x_bar write slot

  // cd body (wid 0..2)
  const int v01 = vty & 1;
  const int aBC = 1460 + 104 * v01 + t;   // bC/bD combo
  const int aEQ = 1252 + t;               // eq[t]
  const int aUM = 1667 + 104 * v01 + t;   // uc[t-1] (t=0 -> guard)
  const float ce = v01 ? cDE : cET;
  const float ctc = v01 ? 0.f : 0.25f;

  // y body (wid 3..5): bases into VB[v], VB[1-v]
  const int yv = (vty >= 2) ? (vty - 2) : 0;
  const int bv = 624 * yv + t;
  const int bw = 624 * (1 - yv) + t;

  // soc body (wid 6..7)
  const float ce1 = (t <= 94) ? -1.f : 1.f;
  const int aBS = 1356 + t;

  // ================= phase B per-thread constants =================
  // BOX: w0 t=lane; w1 lanes<32 t=64+lane
  const int tb = (wid == 0) ? lane : (64 + (lane & 31));
  const bool isBox = (wid == 0) || (wid == 1 && lane < 32);
  // EQ: w1 lanes>=32 r=0..31; w5 all r=32..95; w7 lane32 r=96
  int er; bool eqRun, eqAct;
  if (wid == 1)      { er = (lane >= 32) ? lane - 32 : 0; eqRun = true; eqAct = (lane >= 32); }
  else if (wid == 5) { er = 32 + lane; eqRun = true; eqAct = true; }
  else if (wid == 7) { er = 96; eqRun = true; eqAct = (lane == 32); }
  else               { er = 0; eqRun = false; eqAct = false; }
  const float cEb = (er == 96) ? -1.f : 1.f;  // r=96: dot = +s[95] via guard at s[96]
  // MD: w2 i=lane, w3 i=64+lane, w4 i=128+lane (i<190)
  const bool mdRun = (wid >= 2) && (wid <= 4);
  const int mi0 = ((wid - 2) << 6) + lane;
  const bool mdAct = mdRun && (mi0 < 190);
  const int mi = mdAct ? mi0 : 189;
  const int mv = (mi >= 95) ? 1 : 0;
  const int mt = mi - 95 * mv;
  const int mx = 104 * (2 + mv) + mt;   // sxb y_v base
  const int mw = 624 * mv + mt;         // sy VB[v] write base
  const float cv2 = (mt <= 93) ? 1.f : 0.f;
  const float cv3 = (mt <= 92) ? 1.f : 0.f;
  // RAMP: w5 t=1..64 (double-duty with eq); w6 lanes<31 t=65..95
  const bool rRun = (wid == 5) || (wid == 6);
  const bool rAct = (wid == 5) || (wid == 6 && lane < 31);
  const int rt = (wid == 5) ? (1 + lane) : (65 + ((lane < 31) ? lane : 30));
  // SW: w6 all t=0..63; w7 lanes<31 t=64..94
  const bool sRun = (wid >= 6);
  const bool sAct = (wid == 6) || (wid == 7 && lane < 31);
  const int st = (wid == 6) ? lane : (64 + ((lane < 31) ? lane : 30));

  // ================= state =================
  float xA = 0.f, qA = 0.f;
  float yb0=0,yb1=0,yb2=0,yb3=0,yb4=0,yb5=0,yb6=0,yb7=0,yb8=0,yb9=0,yb10=0,yb11=0,yb12=0;
  float ym1=0, ym2=0, ym3=0, yr0=0, yr1=0, yr2=0, yr3=0, ysw0=0, ysw1=0, yeq=0, ytc=0;

  auto gatherA = [&]() -> float {
    if (wid < 3) {
      float b = sy[aBC], e = sy[aEQ];
      float um = sy[aUM], up = sy[aUM + 1];
      float tc = sy[1872];
      return b + ce * e + um - up + ctc * tc;
    } else if (wid < 6) {
      float k1 = sy[bv + 3], k2 = sy[bv + 106], k3 = sy[bv + 209];
      float m0 = sy[bv + 316], m1 = sy[bv + 317];
      float bY = sy[bv + 420], s0 = sy[bv + 524], s1 = sy[bw + 523];
      return bY + s0 + s1 + (m0 - m1) - (k1 + k2 + k3);
    } else {
      float e0 = sy[aEQ], e1 = sy[aEQ + 1], bS = sy[aBS];
      return bS + e0 + ce1 * e1;
    }
  };

  // full phase B with sigma (power selects raw dots)
  float tauv = 0.f, sigv = 0.f;
  auto phaseBfull = [&](bool power) {
    const float sig = sigv;
    if (wid <= 1) {  // BOX
      float c_ = sxb[4 + tb], d_ = sxb[108 + tb];
      float yc_ = sxb[212 + tb], yd_ = sxb[316 + tb], s_ = sxb[420 + tb];
      float v0,v1,v2,v3,v4,v5,v6,v7,v8,v9,v10,v11,v12;
      if (power) {
        v0=c_; v1=d_; v2=-c_; v3=-d_; v4=-yc_; v5=yc_; v6=-yd_; v7=yd_;
        v8=-s_; v9=s_; v10=yc_+yd_; v11=c_-195.f*yc_; v12=d_-195.f*yd_;
      } else {
        yb0  = fmaxf(yb0  + sig*(c_  - 195.f), 0.f);      v0 = yb0;
        yb1  = fmaxf(yb1  + sig*(d_  - 195.f), 0.f);      v1 = yb1;
        yb2  = fmaxf(yb2  - sig*c_,            0.f);      v2 = yb2;
        yb3  = fmaxf(yb3  - sig*d_,            0.f);      v3 = yb3;
        yb4  = fmaxf(yb4  - sig*yc_,           0.f);      v4 = yb4;
        yb5  = fmaxf(yb5  + sig*(yc_ - 1.f),   0.f);      v5 = yb5;
        yb6  = fmaxf(yb6  - sig*yd_,           0.f);      v6 = yb6;
        yb7  = fmaxf(yb7  + sig*(yd_ - 1.f),   0.f);      v7 = yb7;
        yb8  = fmaxf(yb8  - sig*s_,            0.f);      v8 = yb8;
        yb9  = fmaxf(yb9  + sig*(s_ - 800.f),  0.f);      v9 = yb9;
        yb10 = fmaxf(yb10 + sig*(yc_ + yd_ - 1.f), 0.f);  v10 = yb10;
        yb11 = fmaxf(yb11 + sig*(c_ - 195.f*yc_), 0.f);   v11 = yb11;
        yb12 = fmaxf(yb12 + sig*(d_ - 195.f*yd_), 0.f);   v12 = yb12;
      }
      if (isBox) {
        sy[1460 + tb] = v0 - v2 + v11;                     // bC
        sy[1564 + tb] = v1 - v3 + v12;                     // bD
        sy[420 + tb]  = -v4 + v5 + v10 - 195.f * v11;      // bYC
        sy[1044 + tb] = -v6 + v7 + v10 - 195.f * v12;      // bYD
        sy[1356 + tb] = -v8 + v9;                          // bS
      }
    }
    if (mdRun) {  // MIN-DURATION: rows (v, k=1..3, mt) + own-sum
      float mp = sxb[mx + 3];                // y_v[t-1] (guard at t=0)
      float mc = sxb[mx + 4], m1v = sxb[mx + 5];
      float m2v = sxb[mx + 6], m3v = sxb[mx + 7];
      float base = mc - mp;
      float d1 = base - m1v, d2 = base - m2v, d3 = base - m3v;
      float o1, o2, o3;
      if (power) { o1 = d1; o2 = d2; o3 = d3; }
      else {
        ym1 = fmaxf(ym1 + sig * d1, 0.f); o1 = ym1;
        ym2 = fmaxf(ym2 + sig * d2, 0.f); o2 = ym2;
        ym3 = fmaxf(ym3 + sig * d3, 0.f); o3 = ym3;
      }
      if (mdAct) {
        sy[mw + 4]   = o1;
        sy[mw + 108] = o2;
        sy[mw + 212] = o3;
        sy[mw + 316] = o1 + cv2 * o2 + cv3 * o3;  // own-sum (valid rows only)
      }
    }
    if (rRun) {  // RAMP: 4 rows -> 2 combos
      float rcm = sxb[3 + rt], rc0 = sxb[4 + rt];
      float rdm = sxb[107 + rt], rd0 = sxb[108 + rt];
      float u0, u1, u2, u3;
      if (power) { u0 = rc0 - rcm; u1 = rcm - rc0; u2 = rd0 - rdm; u3 = rdm - rd0; }
      else {
        yr0 = fmaxf(yr0 + sig * (rc0 - rcm - 65.f), 0.f); u0 = yr0;
        yr1 = fmaxf(yr1 + sig * (rcm - rc0 - 65.f), 0.f); u1 = yr1;
        yr2 = fmaxf(yr2 + sig * (rd0 - rdm - 65.f), 0.f); u2 = yr2;
        yr3 = fmaxf(yr3 + sig * (rdm - rd0 - 65.f), 0.f); u3 = yr3;
      }
      if (rAct) { sy[1667 + rt] = u0 - u1; sy[1771 + rt] = u2 - u3; }
    }
    if (sRun) {  // SWITCH: 2 raw rows
      float a0 = sxb[212 + st], a1 = sxb[213 + st];
      float b0 = sxb[316 + st], b1 = sxb[317 + st];
      float p0, p1;
      if (power) { p0 = a0 + b1; p1 = b0 + a1; }
      else {
        ysw0 = fmaxf(ysw0 + sig * (a0 + b1 - 1.f), 0.f); p0 = ysw0;
        ysw1 = fmaxf(ysw1 + sig * (b0 + a1 - 1.f), 0.f); p1 = ysw1;
      }
      if (sAct) { sy[524 + st] = p0; sy[1148 + st] = p1; }
    }
    if (eqRun) {  // EQUALITY (free dual); r=96 handled by guards + cEb=-1
      float ep = sxb[419 + er], ecur = sxb[420 + er];
      float exc = sxb[4 + er], exd = sxb[108 + er];
      float dot = ecur - cEb * ep + cET * exc + cDE * exd;
      float ev;
      if (power) ev = dot;
      else { yeq += sig * dot; ev = yeq; }
      if (eqAct) sy[1252 + er] = ev;
    }
    if (wid == 7) {  // TOTAL-CHARGE: DPP reduce (VALU pipe, ~60cy) instead of
                     // 6 dependent ds_swizzles (~300-600cy straggler chain)
      float ssum = sxb[4 + lane] + ((lane < 32) ? sxb[68 + lane] : 0.f);
      float tot = wave_sum64(ssum);   // broadcast via readlane -> uniform
      float wv;
      if (power) wv = 0.25f * tot;
      else { ytc = fmaxf(ytc + sig * (0.25f * tot - 1200.f), 0.f); wv = ytc; }
      if (lane == 0) sy[1872] = wv;
    }
  };

  // ================= power iteration: ||K||_2 =================
  for (int i = tid; i < NY; i += 512) sy[i] = 0.f;
  for (int i = tid; i < NX; i += 512) sxb[i] = 0.f;
  __syncthreads();
  if (colAct) sxb[wX] = 1.f;
  __syncthreads();

  float lam2 = 1.f;
  for (int pit = 0; pit < PITER; ++pit) {
    phaseBfull(true);                      // sy = combined(K v)
    __syncthreads();
    float gA = gatherA();                  // (K^T K v) per column
    if (!colAct) gA = 0.f;
    float part = wave_sum64(gA * gA);      // DPP reduce (was 6x __shfl_xor)
    if (lane == 0) s_red[wid] = part;
    __syncthreads();
    lam2 = sqrtf(s_red[0] + s_red[1] + s_red[2] + s_red[3]
               + s_red[4] + s_red[5] + s_red[6] + s_red[7]);
    float inv = 1.f / lam2;
    if (colAct) sxb[wX] = gA * inv;
    __syncthreads();
  }
  tauv = (float)(0.9 / sqrt((double)lam2));
  sigv = tauv;

  // ================= PDHG =================
  for (int i = tid; i < NY; i += 512) sy[i] = 0.f;
  if (tid < 96)       qA =  0.25f * price[bi * 96 + tid];
  else if (tid < 192) qA = -0.25f * price[bi * 96 + (tid - 96)];
  __syncthreads();

#pragma unroll 1
  for (int it = 0; it < NITER; ++it) {
    float gA = gatherA();
    if (colAct) {
      float xa = xA - tauv * (qA + gA);
      sxb[wX] = 2.f * xa - xA;
      xA = xa;
    }
    __syncthreads();
    phaseBfull(false);
    __syncthreads();
  }

  // output: c then d, each (256,96)
  if (tid < 96)       out[bi * 96 + tid] = xA;
  else if (tid < 192) out[24576 + bi * 96 + (tid - 96)] = xA;
}

extern "C" void kernel_launch(void* const* d_in, const int* in_sizes, int n_in,
                              void* d_out, int out_size, void* d_ws, size_t ws_size,
                              hipStream_t stream) {
  const float* price = (const float*)d_in[0];
  float* outp = (float*)d_out;
  hipLaunchKernelGGL(lp_solve_kernel, dim3(256), dim3(512), 0, stream, price, outp);
}